// Round 2
// baseline (21461.256 us; speedup 1.0000x reference)
//
#include <hip/hip_runtime.h>

#define EPS 1e-5f

__device__ __forceinline__ float logsig(float z) {
    // log(sigmoid(z)) = min(z,0) - log1p(exp(-|z|))
    return fminf(z, 0.0f) - log1pf(__expf(-fabsf(z)));
}

// One block = one sequence. 256 threads = 4 waves = 4 heads.
// PSTRIDE==1  : intra pass (seq over q, SLEN=128, fixed t)
// PSTRIDE==128: inter pass (seq over t, SLEN=256, fixed q)
template<int SLEN, int PSTRIDE>
__global__ __launch_bounds__(256, 1)
void gla_pass(const float* __restrict__ src, float* __restrict__ out,
              const float* __restrict__ gamma, const float* __restrict__ beta,
              const float* __restrict__ Wq, const float* __restrict__ Wk,
              const float* __restrict__ Wv, const float* __restrict__ Wg1,
              const float* __restrict__ Wg2, const float* __restrict__ Wr,
              const float* __restrict__ gn, const float* __restrict__ Wo,
              const float* __restrict__ ctw, const float* __restrict__ ctb)
{
    constexpr int NC = SLEN / 32;
    constexpr int L  = SLEN - 1;
    static_assert(SLEN % 32 == 0, "");

    __shared__ float sxc[64][36];     // LN'd slab window (33 cols used; 36 for b128 align)
    __shared__ float qf[32][256];     // q, then q*exp(gc)          fp32
    __shared__ float kf[32][256];     // k, then k*exp(-gc)         fp32
    __shared__ float voc[32][256];    // v until vcol snapshot; then o (normed), then o*silu(r)
    __shared__ float uni[8832];       // union: Ats[4][32][36] (4608 f) + gdec[32][132] (4224 f)
    __shared__ float fw1t[32][36];    // (f @ Wg1) transposed: fw1t[m][t]
    __shared__ float egl[256];        // exp(chunk-total gate)
    __shared__ float sgam[64], sbet[64];
    __shared__ float gprevs[128];     // deconv carry row (fp32)

    float* const Ats  = uni;          // head*1152 + t*36 + s
    float* const gdec = uni + 4608;   // row*132 + c

    const int tid  = threadIdx.x;
    const int lane = tid & 63;
    const int wv   = tid >> 6;        // wave id == head id
    const int n    = blockIdx.x;

    int b, fixedoff;
    if constexpr (PSTRIDE == 1) { b = n >> 8; fixedoff = (n & 255) * 128; }
    else                        { b = n >> 7; fixedoff = (n & 127); }
    const int cbase = (b * 64) * 32768 + fixedoff;   // + c*32768 + p*PSTRIDE

    if (tid < 64)  { sgam[tid] = gamma[tid]; sbet[tid] = beta[tid]; }
    if (tid < 128) gprevs[tid] = 0.0f;

    float S[64];                       // state column v=lane, head=wv (fp32, regs)
    #pragma unroll
    for (int k = 0; k < 64; ++k) S[k] = 0.0f;

    const float gnv = gn[tid];         // gn[head*64 + lane]
    const float bias = ctb[lane];

    for (int ch = 0; ch < NC; ++ch) {
        const int l0 = ch * 32;
        __syncthreads();

        // ---- A: load 33-column slab window ----
        for (int idx = tid; idx < 64 * 33; idx += 256) {
            int cc = idx / 33;
            int i  = idx - cc * 33;
            int p  = l0 + i; if (p > SLEN - 1) p = SLEN - 1;
            sxc[cc][i] = src[cbase + cc * 32768 + p * PSTRIDE];
        }
        __syncthreads();

        // ---- B: LayerNorm over channels, per column ----
        if (tid < 33) {
            float mu = 0.0f;
            for (int cc = 0; cc < 64; ++cc) mu += sxc[cc][tid];
            mu *= (1.0f / 64.0f);
            float var = 0.0f;
            for (int cc = 0; cc < 64; ++cc) { float d = sxc[cc][tid] - mu; var += d * d; }
            var *= (1.0f / 64.0f);
            float inv = rsqrtf(var + EPS);
            for (int cc = 0; cc < 64; ++cc)
                sxc[cc][tid] = (sxc[cc][tid] - mu) * inv * sgam[cc] + sbet[cc];
        }
        __syncthreads();

        // ---- C: fused q,k,v projections (thread = output column d) ----
        {
            const int d = tid;
            float aq[32], ak[32], av[32];
            #pragma unroll
            for (int t = 0; t < 32; ++t) { aq[t] = 0.0f; ak[t] = 0.0f; av[t] = 0.0f; }
            for (int cc = 0; cc < 64; ++cc) {
                float col[33];
                #pragma unroll
                for (int i = 0; i < 8; ++i) {
                    float4 c4 = *(const float4*)&sxc[cc][4 * i];
                    col[4*i] = c4.x; col[4*i+1] = c4.y; col[4*i+2] = c4.z; col[4*i+3] = c4.w;
                }
                col[32] = sxc[cc][32];
                const float wq0 = Wq[(2*cc)*256 + d], wq1 = Wq[(2*cc+1)*256 + d];
                const float wk0 = Wk[(2*cc)*256 + d], wk1 = Wk[(2*cc+1)*256 + d];
                const float wv0 = Wv[(2*cc)*256 + d], wv1 = Wv[(2*cc+1)*256 + d];
                #pragma unroll
                for (int t = 0; t < 32; ++t) {
                    aq[t] += col[t] * wq0 + col[t+1] * wq1;
                    ak[t] += col[t] * wk0 + col[t+1] * wk1;
                    av[t] += col[t] * wv0 + col[t+1] * wv1;
                }
            }
            #pragma unroll
            for (int t = 0; t < 32; ++t) {
                bool valid = (l0 + t) < L;
                qf[t][d]  = valid ? aq[t] * 0.125f : 0.0f;   // * Dk^-0.5
                kf[t][d]  = valid ? ak[t] : 0.0f;
                voc[t][d] = valid ? av[t] : 0.0f;
            }
        }

        // ---- gate part 1: fw1t[m][t] = (f @ Wg1)[t][m] ----
        {
            const int m = tid & 31, tg2 = tid >> 5;   // tg2 in [0,8)
            float a4[4] = {0.0f, 0.0f, 0.0f, 0.0f};
            for (int cc = 0; cc < 64; ++cc) {
                const float w0 = Wg1[(2*cc)*32 + m], w1 = Wg1[(2*cc+1)*32 + m];
                #pragma unroll
                for (int i = 0; i < 4; ++i) {
                    const int t = tg2 + i * 8;
                    a4[i] += sxc[cc][t] * w0 + sxc[cc][t+1] * w1;
                }
            }
            #pragma unroll
            for (int i = 0; i < 4; ++i) fw1t[m][tg2 + i * 8] = a4[i];
        }
        __syncthreads();

        // ---- gate part 2 (per column d, all in regs):
        //      gk = logsig(fw1 @ Wg2)/32, cumsum, fold exp(+-gc) into q/k, egl ----
        {
            const int d = tid;
            float acc2[32];
            #pragma unroll
            for (int t = 0; t < 32; ++t) acc2[t] = 0.0f;
            for (int mm = 0; mm < 32; ++mm) {
                const float w = Wg2[mm * 256 + d];
                #pragma unroll
                for (int i = 0; i < 8; ++i) {
                    float4 f4 = *(const float4*)&fw1t[mm][4 * i];
                    acc2[4*i+0] += f4.x * w; acc2[4*i+1] += f4.y * w;
                    acc2[4*i+2] += f4.z * w; acc2[4*i+3] += f4.w * w;
                }
            }
            float run = 0.0f;
            #pragma unroll
            for (int t = 0; t < 32; ++t) {
                if ((l0 + t) < L) run += logsig(acc2[t]) * (1.0f / 32.0f);
                qf[t][d] *= __expf(run);
                kf[t][d] *= __expf(-run);
            }
            egl[d] = __expf(run);
        }
        __syncthreads();

        // ---- F: per-wave (=per-head) attention ----
        const int base = wv * 64;
        float vcol[32];
        #pragma unroll
        for (int t = 0; t < 32; ++t) vcol[t] = voc[t][base + lane];

        // F1: triangular scores A[t][s] = sum_d qi[t][d]*ke[s][d]
        for (int pi = lane; pi < 528; pi += 64) {
            float fpi = (float)pi;
            int t = (int)((sqrtf(8.0f * fpi + 1.0f) - 1.0f) * 0.5f);
            if (((t + 1) * (t + 2)) / 2 <= pi) ++t;
            if ((t * (t + 1)) / 2 > pi) --t;
            int s = pi - (t * (t + 1)) / 2;
            float a = 0.0f;
            #pragma unroll
            for (int ii = 0; ii < 16; ++ii) {
                int i = (ii + lane) & 15;          // rotate to spread LDS bank groups
                float4 q4 = *(const float4*)&qf[t][base + 4 * i];
                float4 k4 = *(const float4*)&kf[s][base + 4 * i];
                a += q4.x*k4.x + q4.y*k4.y + q4.z*k4.z + q4.w*k4.w;
            }
            Ats[wv * 1152 + t * 36 + s] = a;
        }
        __syncthreads();

        // F2: o = o_intra + o_inter ; F3: RMS-norm per (t,head) + store into voc
        {
            float ot[32];
            #pragma unroll
            for (int t = 0; t < 32; ++t) {
                float oi = 0.0f;
                for (int s = 0; s <= t; ++s) oi += Ats[wv * 1152 + t * 36 + s] * vcol[s];
                float oe = 0.0f;
                #pragma unroll
                for (int i = 0; i < 16; ++i) {
                    float4 q4 = *(const float4*)&qf[t][base + 4 * i];
                    oe += q4.x*S[4*i] + q4.y*S[4*i+1] + q4.z*S[4*i+2] + q4.w*S[4*i+3];
                }
                ot[t] = oi + oe;
            }
            // F4: S = exp(gl) * (S + ke^T v)   (before voc is overwritten)
            float sacc[64];
            #pragma unroll
            for (int k = 0; k < 64; ++k) sacc[k] = 0.0f;
            for (int t = 0; t < 32; ++t) {
                const float vt = vcol[t];
                #pragma unroll
                for (int i = 0; i < 16; ++i) {
                    float4 k4 = *(const float4*)&kf[t][base + 4 * i];
                    sacc[4*i+0] += k4.x * vt; sacc[4*i+1] += k4.y * vt;
                    sacc[4*i+2] += k4.z * vt; sacc[4*i+3] += k4.w * vt;
                }
            }
            #pragma unroll
            for (int k = 0; k < 64; ++k) S[k] = egl[base + k] * (S[k] + sacc[k]);
            // F3: RMS-norm rows, write o into voc
            #pragma unroll
            for (int t = 0; t < 32; ++t) {
                float ss = ot[t] * ot[t];
                #pragma unroll
                for (int off = 32; off > 0; off >>= 1) ss += __shfl_xor(ss, off, 64);
                voc[t][base + lane] = ot[t] * rsqrtf(ss * (1.0f / 64.0f) + EPS) * gnv;
            }
        }
        __syncthreads();

        // ---- G: r = f @ Wr ; voc *= silu(r) ----
        {
            const int d = tid;
            float ar[32];
            #pragma unroll
            for (int t = 0; t < 32; ++t) ar[t] = 0.0f;
            for (int cc = 0; cc < 64; ++cc) {
                float col[33];
                #pragma unroll
                for (int i = 0; i < 8; ++i) {
                    float4 c4 = *(const float4*)&sxc[cc][4 * i];
                    col[4*i] = c4.x; col[4*i+1] = c4.y; col[4*i+2] = c4.z; col[4*i+3] = c4.w;
                }
                col[32] = sxc[cc][32];
                const float w0 = Wr[(2*cc)*256 + d], w1 = Wr[(2*cc+1)*256 + d];
                #pragma unroll
                for (int t = 0; t < 32; ++t) ar[t] += col[t] * w0 + col[t+1] * w1;
            }
            #pragma unroll
            for (int t = 0; t < 32; ++t) {
                const float r = ar[t];
                voc[t][d] *= r / (1.0f + __expf(-r));
            }
        }
        __syncthreads();

        // ---- H: gdec = oc @ Wo ----
        {
            const int m  = tid & 127;
            const int tg = tid >> 7;          // rows 0..15 / 16..31 (wave-uniform)
            float acc[16];
            #pragma unroll
            for (int i = 0; i < 16; ++i) acc[i] = 0.0f;
            for (int j = 0; j < 256; j += 4) {
                const float w0 = Wo[(j+0)*128 + m];
                const float w1 = Wo[(j+1)*128 + m];
                const float w2 = Wo[(j+2)*128 + m];
                const float w3 = Wo[(j+3)*128 + m];
                #pragma unroll
                for (int i = 0; i < 16; ++i) {
                    float4 o4 = *(const float4*)&voc[tg * 16 + i][j];
                    acc[i] += o4.x*w0 + o4.y*w1 + o4.z*w2 + o4.w*w3;
                }
            }
            #pragma unroll
            for (int i = 0; i < 16; ++i) gdec[(tg * 16 + i) * 132 + m] = acc[i];
        }
        __syncthreads();

        // ---- I: deconv1d (K=2) + bias + residual + store ----
        {
            const int o  = lane;
            const int pg = wv;                 // 4 row-groups of 8
            const float2* ctw2 = (const float2*)ctw;   // [cin][o] -> (w_k0, w_k1)
            #pragma unroll
            for (int i = 0; i < 8; ++i) {
                const int tl = pg * 8 + i;
                const float* cur  = gdec + tl * 132;
                const float* prev = (tl > 0) ? (gdec + (tl - 1) * 132) : gprevs;
                float acc = bias;
                for (int cin = 0; cin < 128; cin += 4) {
                    float4 c4 = *(const float4*)&cur[cin];
                    float4 p4 = *(const float4*)&prev[cin];
                    float2 wa = ctw2[(cin+0)*64 + o];
                    float2 wb = ctw2[(cin+1)*64 + o];
                    float2 wc = ctw2[(cin+2)*64 + o];
                    float2 wd = ctw2[(cin+3)*64 + o];
                    acc += c4.x*wa.x + p4.x*wa.y + c4.y*wb.x + p4.y*wb.y
                         + c4.z*wc.x + p4.z*wc.y + c4.w*wd.x + p4.w*wd.y;
                }
                const int p  = l0 + tl;
                const int oi = cbase + o * 32768 + p * PSTRIDE;
                out[oi] = acc + src[oi];
            }
        }
        __syncthreads();
        if (tid < 128) gprevs[tid] = gdec[31 * 132 + tid];   // carry for next chunk
    }
}

extern "C" void kernel_launch(void* const* d_in, const int* in_sizes, int n_in,
                              void* d_out, int out_size, void* d_ws, size_t ws_size,
                              hipStream_t stream)
{
    const float* x = (const float*)d_in[0];
    // d_in[1] = mouth (unused by the reference forward)
    float* y = (float*)d_ws;     // intermediate after intra pass: 4*64*256*128 fp32
    float* z = (float*)d_out;

    // intra pass: sequences over q (fixed t), SLEN = Q = 128, grid = B*T = 1024
    gla_pass<128, 1><<<dim3(1024), dim3(256), 0, stream>>>(
        x, y,
        (const float*)d_in[2],  (const float*)d_in[3],  (const float*)d_in[4],
        (const float*)d_in[5],  (const float*)d_in[6],  (const float*)d_in[7],
        (const float*)d_in[8],  (const float*)d_in[9],  (const float*)d_in[10],
        (const float*)d_in[11], (const float*)d_in[12], (const float*)d_in[13]);

    // inter pass: sequences over t (fixed q), SLEN = T = 256, grid = B*Q = 512
    gla_pass<256, 128><<<dim3(512), dim3(256), 0, stream>>>(
        y, z,
        (const float*)d_in[14], (const float*)d_in[15], (const float*)d_in[16],
        (const float*)d_in[17], (const float*)d_in[18], (const float*)d_in[19],
        (const float*)d_in[20], (const float*)d_in[21], (const float*)d_in[22],
        (const float*)d_in[23], (const float*)d_in[24], (const float*)d_in[25]);
}